// Round 8
// baseline (175.411 us; speedup 1.0000x reference)
//
#include <hip/hip_runtime.h>
#include <hip/hip_bf16.h>

// SparseAttention B=1,H=8,S=4096,D=32 fp32; mask [S,S] as int32.
// MFMA bf16 flash, split-hi/lo QK (fp32-quality scores), PV bf16.
// R8: in-block k-split (8 waves: 0-3 = kt[0,32), 4-7 = kt[32,64), LDS
// combine epilogue -> no combine kernel / no po round-trip); l via
// ones-MFMA row-sum (VALU->MFMA pipe shift). No inline asm near MFMA
// results (software-managed hazards; R4/R6 lesson).

#define S_  4096
#define D_  32
#define H_  8

typedef short short8 __attribute__((ext_vector_type(8)));
typedef short short4v __attribute__((ext_vector_type(4)));
typedef float float4v __attribute__((ext_vector_type(4)));
typedef unsigned short ushort_t;
typedef unsigned int u32;

__device__ inline ushort_t f2bf(float x) {
    __hip_bfloat16 h = __float2bfloat16(x);
    return *(ushort_t*)&h;
}
__device__ inline float bf2f(ushort_t u) {
    __hip_bfloat16 h; *(ushort_t*)&h = u; return __bfloat162float(h);
}
__device__ inline u32 fbits(float x) {
    union { float f; u32 u; } c; c.f = x; return c.u;
}
__device__ inline void hilo(float v, ushort_t& h, ushort_t& lo) {
    h = f2bf(v);
    lo = f2bf(v - bf2f(h));
}

// ---------------- fused pre-pass (one launch, vectorized) ----------------
// blocks [0,512): Q hi/lo row-major, scale*log2e folded (8 elems/thread)
// blocks [512,1024): K hi/lo frag-major [h][kt][t16][quad][n][j]
// blocks [1024,1536): V frag-major [h][kt][khalf][dhalf][quad][n][j], rows
//   k-PERMUTED: frag k-pos p holds row (p&3)*16 + (p>>2)
// blocks [1536,5632): mask -> per-lane u16 mlane[qt16][kt][lane],
//   bit (t16*4+reg) = mask[qt16*16+(lane>>4)*4+reg][kt*64+t16*16+(lane&15)]
__global__ __launch_bounds__(256)
void prepass(const float* __restrict__ Q, const float* __restrict__ K,
             const float* __restrict__ V, const int* __restrict__ mask,
             ushort_t* __restrict__ Qhi, ushort_t* __restrict__ Qlo,
             ushort_t* __restrict__ Khi, ushort_t* __restrict__ Klo,
             ushort_t* __restrict__ Vt, ushort_t* __restrict__ mlane)
{
    const int bx = blockIdx.x;
    const int tid = threadIdx.x;
    union U8 { ushort_t u[8]; short8 v; };

    if (bx < 512) {
        const int e0 = (bx * 256 + tid) * 8;
        const float c = 0.17677669529663687f * 1.4426950408889634f;
        float4 a = *(const float4*)(Q + e0);
        float4 b = *(const float4*)(Q + e0 + 4);
        float f[8] = {a.x*c, a.y*c, a.z*c, a.w*c, b.x*c, b.y*c, b.z*c, b.w*c};
        U8 hi, lo;
#pragma unroll
        for (int i = 0; i < 8; ++i) hilo(f[i], hi.u[i], lo.u[i]);
        *(short8*)(Qhi + e0) = hi.v;
        *(short8*)(Qlo + e0) = lo.v;
    } else if (bx < 1024) {
        const int e0 = ((bx - 512) * 256 + tid) * 8;
        const int n = (e0 >> 3) & 15, quad = (e0 >> 7) & 3, t16 = (e0 >> 9) & 3;
        const int kt = (e0 >> 11) & 63, h = e0 >> 17;
        const int krow = kt * 64 + t16 * 16 + n;
        const float* src = K + ((size_t)h * S_ + krow) * D_ + quad * 8;
        float4 a = *(const float4*)src;
        float4 b = *(const float4*)(src + 4);
        float f[8] = {a.x, a.y, a.z, a.w, b.x, b.y, b.z, b.w};
        U8 hi, lo;
#pragma unroll
        for (int i = 0; i < 8; ++i) hilo(f[i], hi.u[i], lo.u[i]);
        *(short8*)(Khi + e0) = hi.v;
        *(short8*)(Klo + e0) = lo.v;
    } else if (bx < 1536) {
        const int e0 = ((bx - 1024) * 256 + tid) * 8;
        const int n = (e0 >> 3) & 15, quad = (e0 >> 7) & 3;
        const int dhalf = (e0 >> 9) & 1, khalf = (e0 >> 10) & 1;
        const int kt = (e0 >> 11) & 63, h = e0 >> 17;
        const int d = dhalf * 16 + n;
        const int pbase = khalf * 32 + quad * 8;
        U8 o;
#pragma unroll
        for (int j = 0; j < 8; ++j) {
            int p = pbase + j;
            int krow = kt * 64 + (p & 3) * 16 + (p >> 2);   // permuted row
            o.u[j] = f2bf(V[((size_t)h * S_ + krow) * D_ + d]);
        }
        *(short8*)(Vt + e0) = o.v;
    } else {
        const int pairi = (bx - 1536) * 4 + (tid >> 6);   // (qt16,kt) in [0,16384)
        const int l = tid & 63;
        const int qt16 = pairi >> 6, kt = pairi & 63;
        const int row0 = qt16 * 16 + (l >> 4) * 4;
        const int col0 = kt * 64 + (l & 15);
        u32 ml = 0;
#pragma unroll
        for (int t16 = 0; t16 < 4; ++t16)
#pragma unroll
            for (int reg = 0; reg < 4; ++reg) {
                int v = mask[(size_t)(row0 + reg) * S_ + col0 + t16 * 16];
                ml |= (v != 0 ? 1u : 0u) << (t16 * 4 + reg);
            }
        mlane[(size_t)pairi * 64 + l] = (ushort_t)ml;
    }
}

// ---------------- main MFMA flash kernel (8 waves, in-block k-split) -----

#define PS_STRIDE 72  // ushorts; 144B rows

__device__ inline void gl_lds16(const ushort_t* g, ushort_t* l) {
    __builtin_amdgcn_global_load_lds((const __attribute__((address_space(1))) void*)g,
                                     (__attribute__((address_space(3))) void*)l,
                                     16, 0, 0);
}

__global__ __launch_bounds__(512, 4)
void attn_mfma(const ushort_t* __restrict__ Qhi, const ushort_t* __restrict__ Qlo,
               const ushort_t* __restrict__ Khi, const ushort_t* __restrict__ Klo,
               const ushort_t* __restrict__ Vt, const ushort_t* __restrict__ mlane,
               float* __restrict__ out)
{
    // staging: Khi[2 halves][2048] | Klo | Vt  (24KB) ; Ps: 8 waves x 1152 (18KB)
    __shared__ __align__(16) ushort_t sm[12288 + 8 * 16 * PS_STRIDE];
    ushort_t* Khi_s = sm;            // [half*2048 + ...]
    ushort_t* Klo_s = sm + 4096;
    ushort_t* Vt_s  = sm + 8192;

    const int h  = blockIdx.y;
    const int q0 = blockIdx.x * 64;
    const int tid = threadIdx.x;
    const int w = tid >> 6, l = tid & 63;
    const int half = w >> 2, wl = w & 3;
    const int n16 = l & 15, quad = l >> 4;

    ushort_t* Ps = sm + 12288 + w * 16 * PS_STRIDE;

    const int qt16_u = __builtin_amdgcn_readfirstlane(blockIdx.x * 4 + wl);
    const ushort_t* mlw = mlane + ((size_t)qt16_u << 12);  // [kt][lane]

    const int qrow = q0 + wl * 16 + n16;
    const size_t qoff = ((size_t)h * S_ + qrow) * D_ + quad * 8;
    const short8 qhi = *(const short8*)(Qhi + qoff);
    const short8 qlo = *(const short8*)(Qlo + qoff);

    // ones B-frag for row-sum mfma (bf16 1.0 = 0x3F80)
    short8 ones;
#pragma unroll
    for (int i = 0; i < 8; ++i) ones[i] = (short)0x3F80;

    float4v o0 = {0.f, 0.f, 0.f, 0.f};
    float4v o1 = {0.f, 0.f, 0.f, 0.f};
    float4v lacc = {0.f, 0.f, 0.f, 0.f};

    const int hbase = half * 2048;

    for (int i = 0; i < 32; ++i) {
        const int kt = half * 32 + i;
        __syncthreads();
        const size_t tb = ((size_t)(h * 64 + kt)) * 2048 + wl * 512 + l * 8;
        gl_lds16(Khi + tb, Khi_s + hbase + wl * 512);
        gl_lds16(Klo + tb, Klo_s + hbase + wl * 512);
        gl_lds16(Vt  + tb, Vt_s  + hbase + wl * 512);

        const u32 ml = mlw[kt * 64 + l];   // per-lane 16 mask bits, coalesced
        __syncthreads();

        float pv[4][4];
#pragma unroll
        for (int t16 = 0; t16 < 4; ++t16) {
            const int fo = hbase + (t16 * 4 + quad) * 128 + n16 * 8;
            const short8 bhi = *(const short8*)(Khi_s + fo);
            const short8 blo = *(const short8*)(Klo_s + fo);
            float4v c = {0.f, 0.f, 0.f, 0.f};
            c = __builtin_amdgcn_mfma_f32_16x16x32_bf16(qhi, bhi, c, 0, 0, 0);
            c = __builtin_amdgcn_mfma_f32_16x16x32_bf16(qhi, blo, c, 0, 0, 0);
            c = __builtin_amdgcn_mfma_f32_16x16x32_bf16(qlo, bhi, c, 0, 0, 0);
#pragma unroll
            for (int reg = 0; reg < 4; ++reg) {
                float e = exp2f(c[reg]);
                pv[t16][reg] = (ml & (1u << (t16 * 4 + reg))) ? e : 0.f;
            }
        }
        // pack 4 t16-values per reg -> one b64 store at permuted positions
        // pos = n16*4 + t16  (P_perm[r][pos] = P[r][(pos&3)*16 + (pos>>2)])
#pragma unroll
        for (int reg = 0; reg < 4; ++reg) {
            u32 b0 = fbits(pv[0][reg]) + 0x8000u;
            u32 b1 = fbits(pv[1][reg]) + 0x8000u;
            u32 b2 = fbits(pv[2][reg]) + 0x8000u;
            u32 b3 = fbits(pv[3][reg]) + 0x8000u;
            u32 lo_ = __builtin_amdgcn_perm(b1, b0, 0x07060302u);
            u32 hi_ = __builtin_amdgcn_perm(b3, b2, 0x07060302u);
            union { u32 wds[2]; short4v s; } pk;
            pk.wds[0] = lo_; pk.wds[1] = hi_;
            *(short4v*)(Ps + (quad * 4 + reg) * PS_STRIDE + n16 * 4) = pk.s;
        }
        // compiler fence: keep P stores ordered before P loads
        asm volatile("" ::: "memory");

#pragma unroll
        for (int khalf = 0; khalf < 2; ++khalf) {
            const short8 pa = *(const short8*)(Ps + n16 * PS_STRIDE + khalf * 32 + quad * 8);
            const short8 v0 = *(const short8*)(Vt_s + hbase + ((khalf * 2 + 0) * 4 + quad) * 128 + n16 * 8);
            const short8 v1 = *(const short8*)(Vt_s + hbase + ((khalf * 2 + 1) * 4 + quad) * 128 + n16 * 8);
            o0 = __builtin_amdgcn_mfma_f32_16x16x32_bf16(pa, v0, o0, 0, 0, 0);
            o1 = __builtin_amdgcn_mfma_f32_16x16x32_bf16(pa, v1, o1, 0, 0, 0);
            lacc = __builtin_amdgcn_mfma_f32_16x16x32_bf16(pa, ones, lacc, 0, 0, 0);
        }
    }

    // ---- block-level combine: half 1 dumps partials, half 0 reduces+stores
    __syncthreads();
    float* red = (float*)sm;            // reuse staging area (8.7KB < 24KB)
    const int RSTR = 16 * 33 + 16;      // per-wl region: o[16][33] + l[16]
    if (half == 1) {
        float* ro = red + wl * RSTR;
#pragma unroll
        for (int reg = 0; reg < 4; ++reg) {
            const int r = quad * 4 + reg;
            ro[r * 33 + n16]      = o0[reg];
            ro[r * 33 + 16 + n16] = o1[reg];
            if (n16 == 0) ro[16 * 33 + r] = lacc[reg];
        }
    }
    __syncthreads();
    if (half == 0) {
        const float* ro = red + wl * RSTR;
#pragma unroll
        for (int reg = 0; reg < 4; ++reg) {
            const int r = quad * 4 + reg;
            const float inv = 1.0f / (lacc[reg] + ro[16 * 33 + r]); // band => >0
            const int row = q0 + wl * 16 + r;
            float* orow = out + ((size_t)h * S_ + row) * D_;
            orow[n16]      = (o0[reg] + ro[r * 33 + n16]) * inv;
            orow[16 + n16] = (o1[reg] + ro[r * 33 + 16 + n16]) * inv;
        }
    }
}

// ---------------- fallback fp32 kernel (proven) ----------------

#define QT 64
#define KT 64
#define NSUB 4
#define KPT 16

__global__ __launch_bounds__(256, 2)
void sparse_attn_fp32(const float* __restrict__ Q, const float* __restrict__ K,
                      const float* __restrict__ V, const int* __restrict__ mask,
                      float* __restrict__ out)
{
    __shared__ float Ks[KT][D_];
    __shared__ float Vs[KT][D_];
    __shared__ float red_o[NSUB][QT][D_ + 1];
    __shared__ float red_l[NSUB][QT];

    const int h = blockIdx.y;
    const int q0 = blockIdx.x * QT;
    const int tid = threadIdx.x;
    const int ql = tid & 63;
    const int sub = tid >> 6;
    const int q = q0 + ql;
    const float scale = 0.17677669529663687f;

    float4 qreg[8];
    const float4* qrow = (const float4*)(Q + ((size_t)h * S_ + q) * D_);
#pragma unroll
    for (int i = 0; i < 8; ++i) qreg[i] = qrow[i];

    float o[D_];
#pragma unroll
    for (int d = 0; d < D_; ++d) o[d] = 0.f;
    float lsum0 = 0.f;

    const float* Kh = K + (size_t)h * S_ * D_;
    const float* Vh = V + (size_t)h * S_ * D_;

    for (int jt = 0; jt < S_; jt += KT) {
        __syncthreads();
        {
            const float4* gK = (const float4*)(Kh + (size_t)jt * D_);
            const float4* gV = (const float4*)(Vh + (size_t)jt * D_);
            float4* sK = (float4*)&Ks[0][0];
            float4* sV = (float4*)&Vs[0][0];
            sK[tid] = gK[tid]; sK[tid + 256] = gK[tid + 256];
            sV[tid] = gV[tid]; sV[tid + 256] = gV[tid + 256];
        }
        __syncthreads();

        int4 m4[4];
        {
            const int4* mr = (const int4*)(mask + (size_t)q * S_ + jt + sub * KPT);
#pragma unroll
            for (int i = 0; i < 4; ++i) m4[i] = mr[i];
        }
        const int* mb = (const int*)m4;

#pragma unroll
        for (int kk = 0; kk < KPT; ++kk) {
            const int jl = sub * KPT + kk;
            const float4* krow = (const float4*)&Ks[jl][0];
            float s = 0.f;
#pragma unroll
            for (int i = 0; i < 8; ++i) {
                float4 kv = krow[i];
                s += qreg[i].x * kv.x + qreg[i].y * kv.y + qreg[i].z * kv.z + qreg[i].w * kv.w;
            }
            const float p = mb[kk] ? __expf(s * scale) : 0.f;
            lsum0 += p;
            const float4* vrow = (const float4*)&Vs[jl][0];
#pragma unroll
            for (int i = 0; i < 8; ++i) {
                float4 vv = vrow[i];
                o[i * 4 + 0] += p * vv.x;
                o[i * 4 + 1] += p * vv.y;
                o[i * 4 + 2] += p * vv.z;
                o[i * 4 + 3] += p * vv.w;
            }
        }
    }

#pragma unroll
    for (int d = 0; d < D_; ++d) red_o[sub][ql][d] = o[d];
    red_l[sub][ql] = lsum0;
    __syncthreads();

    const int eq = tid & 63;
    const int dg = tid >> 6;
    float acc[8];
#pragma unroll
    for (int i = 0; i < 8; ++i) acc[i] = 0.f;
    float lsum = 0.f;
#pragma unroll
    for (int s2 = 0; s2 < NSUB; ++s2) {
        lsum += red_l[s2][eq];
#pragma unroll
        for (int i = 0; i < 8; ++i) acc[i] += red_o[s2][eq][dg * 8 + i];
    }
    const float inv = 1.0f / lsum;
    float* orow = out + ((size_t)h * S_ + q0 + eq) * D_ + dg * 8;
#pragma unroll
    for (int i = 0; i < 8; ++i) orow[i] = acc[i] * inv;
}

// ---------------- host ----------------

extern "C" void kernel_launch(void* const* d_in, const int* in_sizes, int n_in,
                              void* d_out, int out_size, void* d_ws, size_t ws_size,
                              hipStream_t stream) {
    const float* Q = (const float*)d_in[0];
    const float* K = (const float*)d_in[1];
    const float* V = (const float*)d_in[2];
    const int* mask = (const int*)d_in[3];
    float* out = (float*)d_out;

    const size_t MB = 1024 * 1024;
    if (ws_size < 12 * MB) {
        dim3 grid(S_ / QT, H_);
        sparse_attn_fp32<<<grid, 256, 0, stream>>>(Q, K, V, mask, out);
        return;
    }

    char* ws = (char*)d_ws;
    ushort_t* Qhi = (ushort_t*)(ws + 0 * MB);
    ushort_t* Qlo = (ushort_t*)(ws + 2 * MB);
    ushort_t* Khi = (ushort_t*)(ws + 4 * MB);
    ushort_t* Klo = (ushort_t*)(ws + 6 * MB);
    ushort_t* Vt  = (ushort_t*)(ws + 8 * MB);
    ushort_t* mlane = (ushort_t*)(ws + 10 * MB); // 2 MB

    prepass<<<5632, 256, 0, stream>>>(Q, K, V, mask, Qhi, Qlo, Khi, Klo, Vt, mlane);

    dim3 grid(S_ / 64, H_);
    attn_mfma<<<grid, 512, 0, stream>>>(Qhi, Qlo, Khi, Klo, Vt, mlane, out);
}

// Round 11
// 163.011 us; speedup vs baseline: 1.0761x; 1.0761x over previous
//
#include <hip/hip_runtime.h>
#include <hip/hip_bf16.h>

// SparseAttention B=1,H=8,S=4096,D=32 fp32; mask [S,S] as int32.
// R11 = R10 + mask-repack grid fix (needs 1024 stripe-blocks: qt16 in [0,256),
// cc in [0,4); R10 launched 256 -> 3/4 of mlane uninitialized -> l=0 -> NaN).
// All-fp16 MFMA flash (fp16 score err ~2^-11 -> no hi/lo split, QK = 1 mfma),
// coalesced LDS-transpose mask repack, in-block k-split, l via ones-MFMA.
// No inline asm near MFMA results (software-managed hazards; R4/R6 lesson).

#define S_  4096
#define D_  32
#define H_  8

typedef _Float16 half8 __attribute__((ext_vector_type(8)));
typedef __fp16 fp16x2 __attribute__((ext_vector_type(2)));
typedef short short8 __attribute__((ext_vector_type(8)));
typedef short short4v __attribute__((ext_vector_type(4)));
typedef float float4v __attribute__((ext_vector_type(4)));
typedef unsigned short ushort_t;
typedef unsigned int u32;

__device__ inline ushort_t f2h(float x) {
    union { _Float16 h; ushort_t u; } c; c.h = (_Float16)x; return c.u;
}

// ---------------- fused pre-pass (one launch) ----------------
// blocks [0,512): Q fp16 row-major, scale*log2e folded (8 elems/thread)
// blocks [512,1024): K fp16 frag-major [h][kt][t16][quad][n][j]
// blocks [1024,1536): V fp16 frag-major [h][kt][khalf][dhalf][quad][n][j],
//   rows k-PERMUTED: frag k-pos p holds row (p&3)*16 + (p>>2)
// blocks [1536,2560): mask -> per-lane u16 mlane[qt16][kt][lane] via LDS
//   transpose; bit (t16*4+reg) = mask[qt16*16+(l>>4)*4+reg][kt*64+t16*16+(l&15)]
__global__ __launch_bounds__(256)
void prepass(const float* __restrict__ Q, const float* __restrict__ K,
             const float* __restrict__ V, const int* __restrict__ mask,
             ushort_t* __restrict__ Qh, ushort_t* __restrict__ Kt,
             ushort_t* __restrict__ Vt, ushort_t* __restrict__ mlane)
{
    __shared__ u32 msh[4096];   // 16 KB: bool bytes for 16 rows x 1024 cols
    const int bx = blockIdx.x;
    const int tid = threadIdx.x;
    union U8 { ushort_t u[8]; short8 v; };

    if (bx < 512) {
        const int e0 = (bx * 256 + tid) * 8;
        const float c = 0.17677669529663687f * 1.4426950408889634f;
        float4 a = *(const float4*)(Q + e0);
        float4 b = *(const float4*)(Q + e0 + 4);
        float f[8] = {a.x*c, a.y*c, a.z*c, a.w*c, b.x*c, b.y*c, b.z*c, b.w*c};
        U8 o;
#pragma unroll
        for (int i = 0; i < 8; ++i) o.u[i] = f2h(f[i]);
        *(short8*)(Qh + e0) = o.v;
    } else if (bx < 1024) {
        const int e0 = ((bx - 512) * 256 + tid) * 8;
        const int n = (e0 >> 3) & 15, quad = (e0 >> 7) & 3, t16 = (e0 >> 9) & 3;
        const int kt = (e0 >> 11) & 63, h = e0 >> 17;
        const int krow = kt * 64 + t16 * 16 + n;
        const float* src = K + ((size_t)h * S_ + krow) * D_ + quad * 8;
        float4 a = *(const float4*)src;
        float4 b = *(const float4*)(src + 4);
        float f[8] = {a.x, a.y, a.z, a.w, b.x, b.y, b.z, b.w};
        U8 o;
#pragma unroll
        for (int i = 0; i < 8; ++i) o.u[i] = f2h(f[i]);
        *(short8*)(Kt + e0) = o.v;
    } else if (bx < 1536) {
        const int e0 = ((bx - 1024) * 256 + tid) * 8;
        const int n = (e0 >> 3) & 15, quad = (e0 >> 7) & 3;
        const int dhalf = (e0 >> 9) & 1, khalf = (e0 >> 10) & 1;
        const int kt = (e0 >> 11) & 63, h = e0 >> 17;
        const int d = dhalf * 16 + n;
        const int pbase = khalf * 32 + quad * 8;
        U8 o;
#pragma unroll
        for (int j = 0; j < 8; ++j) {
            int p = pbase + j;
            int krow = kt * 64 + (p & 3) * 16 + (p >> 2);   // permuted row
            o.u[j] = f2h(V[((size_t)h * S_ + krow) * D_ + d]);
        }
        *(short8*)(Vt + e0) = o.v;
    } else {
        // mask stripe: 16 rows x 1024 cols; 256 qt16 x 4 col-chunks = 1024 blocks
        const int mb = bx - 1536;             // [0,1024)
        const int qt16 = mb >> 2, cc = mb & 3;
        // phase 1: fully-coalesced int4 reads -> bool bytes in LDS
#pragma unroll
        for (int i = 0; i < 16; ++i) {
            int4 m4 = *(const int4*)(mask + (size_t)(qt16 * 16 + i) * S_ + cc * 1024 + tid * 4);
            u32 v = (m4.x != 0 ? 1u : 0u) | (m4.y != 0 ? 0x100u : 0u)
                  | (m4.z != 0 ? 0x10000u : 0u) | (m4.w != 0 ? 0x1000000u : 0u);
            msh[i * 256 + tid] = v;
        }
        __syncthreads();
        // phase 2: assemble 4 u16 words per thread (one kt x 4 lanes)
        const int kt_local = tid >> 4, j = tid & 15;
        const int quad = j >> 2, n2 = j & 3;
        u32 o16[4] = {0, 0, 0, 0};
#pragma unroll
        for (int t16 = 0; t16 < 4; ++t16)
#pragma unroll
            for (int reg = 0; reg < 4; ++reg) {
                u32 v = msh[(quad * 4 + reg) * 256 + kt_local * 16 + t16 * 4 + n2];
                const int bp = t16 * 4 + reg;
                o16[0] |= (v & 1u) << bp;
                o16[1] |= ((v >> 8) & 1u) << bp;
                o16[2] |= ((v >> 16) & 1u) << bp;
                o16[3] |= ((v >> 24) & 1u) << bp;
            }
        union { u32 w[2]; short4v s; } pk;
        pk.w[0] = o16[0] | (o16[1] << 16);
        pk.w[1] = o16[2] | (o16[3] << 16);
        const int kt = cc * 16 + kt_local;
        *(short4v*)(mlane + ((size_t)(qt16 * 64 + kt) * 64 + j * 4)) = pk.s;
    }
}

// ---------------- main MFMA flash kernel (8 waves, in-block k-split) -----

#define PS_STRIDE 72  // fp16 elems; 144B rows

__device__ inline void gl_lds16(const ushort_t* g, ushort_t* l) {
    __builtin_amdgcn_global_load_lds((const __attribute__((address_space(1))) void*)g,
                                     (__attribute__((address_space(3))) void*)l,
                                     16, 0, 0);
}

__global__ __launch_bounds__(512, 4)
void attn_mfma(const ushort_t* __restrict__ Qh, const ushort_t* __restrict__ Kt,
               const ushort_t* __restrict__ Vt, const ushort_t* __restrict__ mlane,
               float* __restrict__ out)
{
    // staging: K[2 halves][2048] | V[2][2048] (16KB) ; Ps: 8 waves x 1152 (18KB)
    __shared__ __align__(16) ushort_t sm[8192 + 8 * 16 * PS_STRIDE];
    ushort_t* K_s  = sm;             // [half*2048 + ...]
    ushort_t* Vt_s = sm + 4096;

    const int h  = blockIdx.y;
    const int q0 = blockIdx.x * 64;
    const int tid = threadIdx.x;
    const int w = tid >> 6, l = tid & 63;
    const int half = w >> 2, wl = w & 3;
    const int n16 = l & 15, quad = l >> 4;

    ushort_t* Ps = sm + 8192 + w * 16 * PS_STRIDE;

    const int qt16_u = __builtin_amdgcn_readfirstlane(blockIdx.x * 4 + wl);
    const ushort_t* mlw = mlane + ((size_t)qt16_u << 12);  // [kt][lane]

    const int qrow = q0 + wl * 16 + n16;
    const half8 qh = *(const half8*)(Qh + ((size_t)h * S_ + qrow) * D_ + quad * 8);

    // ones B-frag for row-sum mfma
    half8 ones;
#pragma unroll
    for (int i = 0; i < 8; ++i) ones[i] = (_Float16)1.0f;

    float4v o0 = {0.f, 0.f, 0.f, 0.f};
    float4v o1 = {0.f, 0.f, 0.f, 0.f};
    float4v lacc = {0.f, 0.f, 0.f, 0.f};

    const int hbase = half * 2048;

    for (int i = 0; i < 32; ++i) {
        const int kt = half * 32 + i;
        __syncthreads();
        const size_t tb = ((size_t)(h * 64 + kt)) * 2048 + wl * 512 + l * 8;
        gl_lds16(Kt + tb, K_s  + hbase + wl * 512);
        gl_lds16(Vt + tb, Vt_s + hbase + wl * 512);

        const u32 ml = mlw[kt * 64 + l];   // per-lane 16 mask bits, coalesced
        __syncthreads();

        float pv[4][4];
#pragma unroll
        for (int t16 = 0; t16 < 4; ++t16) {
            const half8 kb = *(const half8*)(K_s + hbase + (t16 * 4 + quad) * 128 + n16 * 8);
            float4v c = {0.f, 0.f, 0.f, 0.f};
            c = __builtin_amdgcn_mfma_f32_16x16x32_f16(qh, kb, c, 0, 0, 0);
#pragma unroll
            for (int reg = 0; reg < 4; ++reg) {
                float e = exp2f(c[reg]);
                pv[t16][reg] = (ml & (1u << (t16 * 4 + reg))) ? e : 0.f;
            }
        }
        // pack 4 t16-values per reg -> one b64 store at permuted positions
        // pos = n16*4 + t16  (P_perm[r][pos] = P[r][(pos&3)*16 + (pos>>2)])
#pragma unroll
        for (int reg = 0; reg < 4; ++reg) {
            fp16x2 h01 = __builtin_amdgcn_cvt_pkrtz(pv[0][reg], pv[1][reg]);
            fp16x2 h23 = __builtin_amdgcn_cvt_pkrtz(pv[2][reg], pv[3][reg]);
            union { fp16x2 h[2]; short4v s; } pk;
            pk.h[0] = h01; pk.h[1] = h23;
            *(short4v*)(Ps + (quad * 4 + reg) * PS_STRIDE + n16 * 4) = pk.s;
        }
        // compiler fence: keep P stores ordered before P loads
        asm volatile("" ::: "memory");

#pragma unroll
        for (int khalf = 0; khalf < 2; ++khalf) {
            const half8 pa = *(const half8*)(Ps + n16 * PS_STRIDE + khalf * 32 + quad * 8);
            const half8 v0 = *(const half8*)(Vt_s + hbase + ((khalf * 2 + 0) * 4 + quad) * 128 + n16 * 8);
            const half8 v1 = *(const half8*)(Vt_s + hbase + ((khalf * 2 + 1) * 4 + quad) * 128 + n16 * 8);
            o0 = __builtin_amdgcn_mfma_f32_16x16x32_f16(pa, v0, o0, 0, 0, 0);
            o1 = __builtin_amdgcn_mfma_f32_16x16x32_f16(pa, v1, o1, 0, 0, 0);
            lacc = __builtin_amdgcn_mfma_f32_16x16x32_f16(pa, ones, lacc, 0, 0, 0);
        }
    }

    // ---- block-level combine: half 1 dumps partials, half 0 reduces+stores
    __syncthreads();
    float* red = (float*)sm;            // reuse staging area (8.7KB < 16KB)
    const int RSTR = 16 * 33 + 16;      // per-wl region: o[16][33] + l[16]
    if (half == 1) {
        float* ro = red + wl * RSTR;
#pragma unroll
        for (int reg = 0; reg < 4; ++reg) {
            const int r = quad * 4 + reg;
            ro[r * 33 + n16]      = o0[reg];
            ro[r * 33 + 16 + n16] = o1[reg];
            if (n16 == 0) ro[16 * 33 + r] = lacc[reg];
        }
    }
    __syncthreads();
    if (half == 0) {
        const float* ro = red + wl * RSTR;
#pragma unroll
        for (int reg = 0; reg < 4; ++reg) {
            const int r = quad * 4 + reg;
            const float inv = 1.0f / (lacc[reg] + ro[16 * 33 + r]); // band => >0
            const int row = q0 + wl * 16 + r;
            float* orow = out + ((size_t)h * S_ + row) * D_;
            orow[n16]      = (o0[reg] + ro[r * 33 + n16]) * inv;
            orow[16 + n16] = (o1[reg] + ro[r * 33 + 16 + n16]) * inv;
        }
    }
}

// ---------------- fallback fp32 kernel (proven) ----------------

#define QT 64
#define KT 64
#define NSUB 4
#define KPT 16

__global__ __launch_bounds__(256, 2)
void sparse_attn_fp32(const float* __restrict__ Q, const float* __restrict__ K,
                      const float* __restrict__ V, const int* __restrict__ mask,
                      float* __restrict__ out)
{
    __shared__ float Ks[KT][D_];
    __shared__ float Vs[KT][D_];
    __shared__ float red_o[NSUB][QT][D_ + 1];
    __shared__ float red_l[NSUB][QT];

    const int h = blockIdx.y;
    const int q0 = blockIdx.x * QT;
    const int tid = threadIdx.x;
    const int ql = tid & 63;
    const int sub = tid >> 6;
    const int q = q0 + ql;
    const float scale = 0.17677669529663687f;

    float4 qreg[8];
    const float4* qrow = (const float4*)(Q + ((size_t)h * S_ + q) * D_);
#pragma unroll
    for (int i = 0; i < 8; ++i) qreg[i] = qrow[i];

    float o[D_];
#pragma unroll
    for (int d = 0; d < D_; ++d) o[d] = 0.f;
    float lsum0 = 0.f;

    const float* Kh = K + (size_t)h * S_ * D_;
    const float* Vh = V + (size_t)h * S_ * D_;

    for (int jt = 0; jt < S_; jt += KT) {
        __syncthreads();
        {
            const float4* gK = (const float4*)(Kh + (size_t)jt * D_);
            const float4* gV = (const float4*)(Vh + (size_t)jt * D_);
            float4* sK = (float4*)&Ks[0][0];
            float4* sV = (float4*)&Vs[0][0];
            sK[tid] = gK[tid]; sK[tid + 256] = gK[tid + 256];
            sV[tid] = gV[tid]; sV[tid + 256] = gV[tid + 256];
        }
        __syncthreads();

        int4 m4[4];
        {
            const int4* mr = (const int4*)(mask + (size_t)q * S_ + jt + sub * KPT);
#pragma unroll
            for (int i = 0; i < 4; ++i) m4[i] = mr[i];
        }
        const int* mb = (const int*)m4;

#pragma unroll
        for (int kk = 0; kk < KPT; ++kk) {
            const int jl = sub * KPT + kk;
            const float4* krow = (const float4*)&Ks[jl][0];
            float s = 0.f;
#pragma unroll
            for (int i = 0; i < 8; ++i) {
                float4 kv = krow[i];
                s += qreg[i].x * kv.x + qreg[i].y * kv.y + qreg[i].z * kv.z + qreg[i].w * kv.w;
            }
            const float p = mb[kk] ? __expf(s * scale) : 0.f;
            lsum0 += p;
            const float4* vrow = (const float4*)&Vs[jl][0];
#pragma unroll
            for (int i = 0; i < 8; ++i) {
                float4 vv = vrow[i];
                o[i * 4 + 0] += p * vv.x;
                o[i * 4 + 1] += p * vv.y;
                o[i * 4 + 2] += p * vv.z;
                o[i * 4 + 3] += p * vv.w;
            }
        }
    }

#pragma unroll
    for (int d = 0; d < D_; ++d) red_o[sub][ql][d] = o[d];
    red_l[sub][ql] = lsum0;
    __syncthreads();

    const int eq = tid & 63;
    const int dg = tid >> 6;
    float acc[8];
#pragma unroll
    for (int i = 0; i < 8; ++i) acc[i] = 0.f;
    float lsum = 0.f;
#pragma unroll
    for (int s2 = 0; s2 < NSUB; ++s2) {
        lsum += red_l[s2][eq];
#pragma unroll
        for (int i = 0; i < 8; ++i) acc[i] += red_o[s2][eq][dg * 8 + i];
    }
    const float inv = 1.0f / lsum;
    float* orow = out + ((size_t)h * S_ + q0 + eq) * D_ + dg * 8;
#pragma unroll
    for (int i = 0; i < 8; ++i) orow[i] = acc[i] * inv;
}

// ---------------- host ----------------

extern "C" void kernel_launch(void* const* d_in, const int* in_sizes, int n_in,
                              void* d_out, int out_size, void* d_ws, size_t ws_size,
                              hipStream_t stream) {
    const float* Q = (const float*)d_in[0];
    const float* K = (const float*)d_in[1];
    const float* V = (const float*)d_in[2];
    const int* mask = (const int*)d_in[3];
    float* out = (float*)d_out;

    const size_t MB = 1024 * 1024;
    if (ws_size < 8 * MB) {
        dim3 grid(S_ / QT, H_);
        sparse_attn_fp32<<<grid, 256, 0, stream>>>(Q, K, V, mask, out);
        return;
    }

    char* ws = (char*)d_ws;
    ushort_t* Qh = (ushort_t*)(ws + 0 * MB);
    ushort_t* Kt = (ushort_t*)(ws + 2 * MB);
    ushort_t* Vt = (ushort_t*)(ws + 4 * MB);
    ushort_t* mlane = (ushort_t*)(ws + 6 * MB);  // 2 MB

    prepass<<<2560, 256, 0, stream>>>(Q, K, V, mask, Qh, Kt, Vt, mlane);

    dim3 grid(S_ / 64, H_);
    attn_mfma<<<grid, 512, 0, stream>>>(Qh, Kt, Vt, mlane, out);
}

// Round 12
// 142.649 us; speedup vs baseline: 1.2297x; 1.1427x over previous
//
#include <hip/hip_runtime.h>
#include <hip/hip_bf16.h>

// SparseAttention B=1,H=8,S=4096,D=32 fp32; mask [S,S] as int32.
// R12: prepass split (prep_qkv / prep_mask) for counter attribution of the
// ~65us prepass mystery; attn K/V double-buffer -> ONE barrier per kt;
// raw v_exp_f32 via __builtin_amdgcn_exp2f (intrinsic, hazard-safe).
// All-fp16 MFMA flash, per-lane u16 mask, perm-packed P, in-block k-split,
// l via ones-MFMA. No inline asm near MFMA results (R4/R6 lesson).

#define S_  4096
#define D_  32
#define H_  8

typedef _Float16 half8 __attribute__((ext_vector_type(8)));
typedef __fp16 fp16x2 __attribute__((ext_vector_type(2)));
typedef short short8 __attribute__((ext_vector_type(8)));
typedef short short4v __attribute__((ext_vector_type(4)));
typedef float float4v __attribute__((ext_vector_type(4)));
typedef unsigned short ushort_t;
typedef unsigned int u32;

#if __has_builtin(__builtin_amdgcn_exp2f)
#define EXP2(x) __builtin_amdgcn_exp2f(x)
#else
#define EXP2(x) exp2f(x)
#endif

__device__ inline ushort_t f2h(float x) {
    union { _Float16 h; ushort_t u; } c; c.h = (_Float16)x; return c.u;
}

// ---------------- pre-pass A: Q/K/V fp16 conversion ----------------
// blocks [0,512): Q fp16 row-major, scale*log2e folded (8 elems/thread)
// blocks [512,1024): K fp16 frag-major [h][kt][t16][quad][n][j]
// blocks [1024,1536): V fp16 frag-major [h][kt][khalf][dhalf][quad][n][j],
//   rows k-PERMUTED: frag k-pos p holds row (p&3)*16 + (p>>2)
__global__ __launch_bounds__(256)
void prep_qkv(const float* __restrict__ Q, const float* __restrict__ K,
              const float* __restrict__ V,
              ushort_t* __restrict__ Qh, ushort_t* __restrict__ Kt,
              ushort_t* __restrict__ Vt)
{
    const int bx = blockIdx.x;
    const int tid = threadIdx.x;
    union U8 { ushort_t u[8]; short8 v; };

    if (bx < 512) {
        const int e0 = (bx * 256 + tid) * 8;
        const float c = 0.17677669529663687f * 1.4426950408889634f;
        float4 a = *(const float4*)(Q + e0);
        float4 b = *(const float4*)(Q + e0 + 4);
        float f[8] = {a.x*c, a.y*c, a.z*c, a.w*c, b.x*c, b.y*c, b.z*c, b.w*c};
        U8 o;
#pragma unroll
        for (int i = 0; i < 8; ++i) o.u[i] = f2h(f[i]);
        *(short8*)(Qh + e0) = o.v;
    } else if (bx < 1024) {
        const int e0 = ((bx - 512) * 256 + tid) * 8;
        const int n = (e0 >> 3) & 15, quad = (e0 >> 7) & 3, t16 = (e0 >> 9) & 3;
        const int kt = (e0 >> 11) & 63, h = e0 >> 17;
        const int krow = kt * 64 + t16 * 16 + n;
        const float* src = K + ((size_t)h * S_ + krow) * D_ + quad * 8;
        float4 a = *(const float4*)src;
        float4 b = *(const float4*)(src + 4);
        float f[8] = {a.x, a.y, a.z, a.w, b.x, b.y, b.z, b.w};
        U8 o;
#pragma unroll
        for (int i = 0; i < 8; ++i) o.u[i] = f2h(f[i]);
        *(short8*)(Kt + e0) = o.v;
    } else {
        const int e0 = ((bx - 1024) * 256 + tid) * 8;
        const int n = (e0 >> 3) & 15, quad = (e0 >> 7) & 3;
        const int dhalf = (e0 >> 9) & 1, khalf = (e0 >> 10) & 1;
        const int kt = (e0 >> 11) & 63, h = e0 >> 17;
        const int d = dhalf * 16 + n;
        const int pbase = khalf * 32 + quad * 8;
        U8 o;
#pragma unroll
        for (int j = 0; j < 8; ++j) {
            int p = pbase + j;
            int krow = kt * 64 + (p & 3) * 16 + (p >> 2);   // permuted row
            o.u[j] = f2h(V[((size_t)h * S_ + krow) * D_ + d]);
        }
        *(short8*)(Vt + e0) = o.v;
    }
}

// ---------------- pre-pass B: mask repack ----------------
// 1024 blocks; mask -> per-lane u16 mlane[qt16][kt][lane] via LDS transpose;
// bit (t16*4+reg) = mask[qt16*16+(l>>4)*4+reg][kt*64+t16*16+(l&15)]
__global__ __launch_bounds__(256)
void prep_mask(const int* __restrict__ mask, ushort_t* __restrict__ mlane)
{
    __shared__ u32 msh[4096];   // 16 KB: bool bytes for 16 rows x 1024 cols
    const int tid = threadIdx.x;
    const int mb = blockIdx.x;            // [0,1024)
    const int qt16 = mb >> 2, cc = mb & 3;
    // phase 1: fully-coalesced int4 reads -> bool bytes in LDS
#pragma unroll
    for (int i = 0; i < 16; ++i) {
        int4 m4 = *(const int4*)(mask + (size_t)(qt16 * 16 + i) * S_ + cc * 1024 + tid * 4);
        u32 v = (m4.x != 0 ? 1u : 0u) | (m4.y != 0 ? 0x100u : 0u)
              | (m4.z != 0 ? 0x10000u : 0u) | (m4.w != 0 ? 0x1000000u : 0u);
        msh[i * 256 + tid] = v;
    }
    __syncthreads();
    // phase 2: assemble 4 u16 words per thread (one kt x 4 lanes)
    const int kt_local = tid >> 4, j = tid & 15;
    const int quad = j >> 2, n2 = j & 3;
    u32 o16[4] = {0, 0, 0, 0};
#pragma unroll
    for (int t16 = 0; t16 < 4; ++t16)
#pragma unroll
        for (int reg = 0; reg < 4; ++reg) {
            u32 v = msh[(quad * 4 + reg) * 256 + kt_local * 16 + t16 * 4 + n2];
            const int bp = t16 * 4 + reg;
            o16[0] |= (v & 1u) << bp;
            o16[1] |= ((v >> 8) & 1u) << bp;
            o16[2] |= ((v >> 16) & 1u) << bp;
            o16[3] |= ((v >> 24) & 1u) << bp;
        }
    union { u32 w[2]; short4v s; } pk;
    pk.w[0] = o16[0] | (o16[1] << 16);
    pk.w[1] = o16[2] | (o16[3] << 16);
    const int kt = cc * 16 + kt_local;
    *(short4v*)(mlane + ((size_t)(qt16 * 64 + kt) * 64 + j * 4)) = pk.s;
}

// ---------------- main MFMA flash kernel (8 waves, dbuf staging) ---------

#define PS_STRIDE 72  // fp16 elems; 144B rows

__device__ inline void gl_lds16(const ushort_t* g, ushort_t* l) {
    __builtin_amdgcn_global_load_lds((const __attribute__((address_space(1))) void*)g,
                                     (__attribute__((address_space(3))) void*)l,
                                     16, 0, 0);
}

__global__ __launch_bounds__(512, 2)
void attn_mfma(const ushort_t* __restrict__ Qh, const ushort_t* __restrict__ Kt,
               const ushort_t* __restrict__ Vt, const ushort_t* __restrict__ mlane,
               float* __restrict__ out)
{
    // K_s [half][buf][2048] 16KB | V_s same 16KB | Ps 8 waves x 1152 18KB
    __shared__ __align__(16) ushort_t sm[16384 + 8 * 16 * PS_STRIDE];
    ushort_t* K_s  = sm;              // half*4096 + buf*2048 + ...
    ushort_t* Vt_s = sm + 8192;

    const int h  = blockIdx.y;
    const int q0 = blockIdx.x * 64;
    const int tid = threadIdx.x;
    const int w = tid >> 6, l = tid & 63;
    const int half = w >> 2, wl = w & 3;
    const int n16 = l & 15, quad = l >> 4;

    ushort_t* Ps = sm + 16384 + w * 16 * PS_STRIDE;

    const int qt16_u = __builtin_amdgcn_readfirstlane(blockIdx.x * 4 + wl);
    const ushort_t* mlw = mlane + ((size_t)qt16_u << 12);  // [kt][lane]

    const int qrow = q0 + wl * 16 + n16;
    const half8 qh = *(const half8*)(Qh + ((size_t)h * S_ + qrow) * D_ + quad * 8);

    half8 ones;
#pragma unroll
    for (int i = 0; i < 8; ++i) ones[i] = (_Float16)1.0f;

    float4v o0 = {0.f, 0.f, 0.f, 0.f};
    float4v o1 = {0.f, 0.f, 0.f, 0.f};
    float4v lacc = {0.f, 0.f, 0.f, 0.f};

    const int hb = half * 4096;
    const int kt_base = half * 32;

    // prologue: stage first tile into buf 0
    {
        const size_t tb = ((size_t)(h * 64 + kt_base)) * 2048 + wl * 512 + l * 8;
        gl_lds16(Kt + tb, K_s  + hb + wl * 512);
        gl_lds16(Vt + tb, Vt_s + hb + wl * 512);
    }
    __syncthreads();

    for (int i = 0; i < 32; ++i) {
        const int kt = kt_base + i;
        const int cb = hb + (i & 1) * 2048;        // current buffer
        // prefetch next tile into other buffer (overlaps with compute;
        // loop-end barrier's vmcnt drain covers it)
        if (i < 31) {
            const int nb = hb + ((i + 1) & 1) * 2048;
            const size_t tb = ((size_t)(h * 64 + kt + 1)) * 2048 + wl * 512 + l * 8;
            gl_lds16(Kt + tb, K_s  + nb + wl * 512);
            gl_lds16(Vt + tb, Vt_s + nb + wl * 512);
        }

        const u32 ml = mlw[kt * 64 + l];   // per-lane 16 mask bits, coalesced

        float pv[4][4];
#pragma unroll
        for (int t16 = 0; t16 < 4; ++t16) {
            const half8 kb = *(const half8*)(K_s + cb + (t16 * 4 + quad) * 128 + n16 * 8);
            float4v c = {0.f, 0.f, 0.f, 0.f};
            c = __builtin_amdgcn_mfma_f32_16x16x32_f16(qh, kb, c, 0, 0, 0);
#pragma unroll
            for (int reg = 0; reg < 4; ++reg) {
                float e = EXP2(c[reg]);
                pv[t16][reg] = (ml & (1u << (t16 * 4 + reg))) ? e : 0.f;
            }
        }
        // pack 4 t16-values per reg -> one b64 store at permuted positions
        // pos = n16*4 + t16  (P_perm[r][pos] = P[r][(pos&3)*16 + (pos>>2)])
#pragma unroll
        for (int reg = 0; reg < 4; ++reg) {
            fp16x2 h01 = __builtin_amdgcn_cvt_pkrtz(pv[0][reg], pv[1][reg]);
            fp16x2 h23 = __builtin_amdgcn_cvt_pkrtz(pv[2][reg], pv[3][reg]);
            union { fp16x2 hh[2]; short4v s; } pk;
            pk.hh[0] = h01; pk.hh[1] = h23;
            *(short4v*)(Ps + (quad * 4 + reg) * PS_STRIDE + n16 * 4) = pk.s;
        }
        // compiler fence: keep P stores ordered before P loads (same-wave)
        asm volatile("" ::: "memory");

#pragma unroll
        for (int khalf = 0; khalf < 2; ++khalf) {
            const half8 pa = *(const half8*)(Ps + n16 * PS_STRIDE + khalf * 32 + quad * 8);
            const half8 v0 = *(const half8*)(Vt_s + cb + ((khalf * 2 + 0) * 4 + quad) * 128 + n16 * 8);
            const half8 v1 = *(const half8*)(Vt_s + cb + ((khalf * 2 + 1) * 4 + quad) * 128 + n16 * 8);
            o0 = __builtin_amdgcn_mfma_f32_16x16x32_f16(pa, v0, o0, 0, 0, 0);
            o1 = __builtin_amdgcn_mfma_f32_16x16x32_f16(pa, v1, o1, 0, 0, 0);
            lacc = __builtin_amdgcn_mfma_f32_16x16x32_f16(pa, ones, lacc, 0, 0, 0);
        }

        // single barrier per iteration: next-buf staging complete (vmcnt)
        // AND all waves done reading cur-buf before it's overwritten
        __syncthreads();
    }

    // ---- block-level combine: half 1 dumps partials, half 0 reduces+stores
    float* red = (float*)sm;            // reuse staging area (8.7KB < 32KB)
    const int RSTR = 16 * 33 + 16;      // per-wl region: o[16][33] + l[16]
    if (half == 1) {
        float* ro = red + wl * RSTR;
#pragma unroll
        for (int reg = 0; reg < 4; ++reg) {
            const int r = quad * 4 + reg;
            ro[r * 33 + n16]      = o0[reg];
            ro[r * 33 + 16 + n16] = o1[reg];
            if (n16 == 0) ro[16 * 33 + r] = lacc[reg];
        }
    }
    __syncthreads();
    if (half == 0) {
        const float* ro = red + wl * RSTR;
#pragma unroll
        for (int reg = 0; reg < 4; ++reg) {
            const int r = quad * 4 + reg;
            const float inv = 1.0f / (lacc[reg] + ro[16 * 33 + r]); // band => >0
            const int row = q0 + wl * 16 + r;
            float* orow = out + ((size_t)h * S_ + row) * D_;
            orow[n16]      = (o0[reg] + ro[r * 33 + n16]) * inv;
            orow[16 + n16] = (o1[reg] + ro[r * 33 + 16 + n16]) * inv;
        }
    }
}

// ---------------- fallback fp32 kernel (proven) ----------------

#define QT 64
#define KT 64
#define NSUB 4
#define KPT 16

__global__ __launch_bounds__(256, 2)
void sparse_attn_fp32(const float* __restrict__ Q, const float* __restrict__ K,
                      const float* __restrict__ V, const int* __restrict__ mask,
                      float* __restrict__ out)
{
    __shared__ float Ks[KT][D_];
    __shared__ float Vs[KT][D_];
    __shared__ float red_o[NSUB][QT][D_ + 1];
    __shared__ float red_l[NSUB][QT];

    const int h = blockIdx.y;
    const int q0 = blockIdx.x * QT;
    const int tid = threadIdx.x;
    const int ql = tid & 63;
    const int sub = tid >> 6;
    const int q = q0 + ql;
    const float scale = 0.17677669529663687f;

    float4 qreg[8];
    const float4* qrow = (const float4*)(Q + ((size_t)h * S_ + q) * D_);
#pragma unroll
    for (int i = 0; i < 8; ++i) qreg[i] = qrow[i];

    float o[D_];
#pragma unroll
    for (int d = 0; d < D_; ++d) o[d] = 0.f;
    float lsum0 = 0.f;

    const float* Kh = K + (size_t)h * S_ * D_;
    const float* Vh = V + (size_t)h * S_ * D_;

    for (int jt = 0; jt < S_; jt += KT) {
        __syncthreads();
        {
            const float4* gK = (const float4*)(Kh + (size_t)jt * D_);
            const float4* gV = (const float4*)(Vh + (size_t)jt * D_);
            float4* sK = (float4*)&Ks[0][0];
            float4* sV = (float4*)&Vs[0][0];
            sK[tid] = gK[tid]; sK[tid + 256] = gK[tid + 256];
            sV[tid] = gV[tid]; sV[tid + 256] = gV[tid + 256];
        }
        __syncthreads();

        int4 m4[4];
        {
            const int4* mr = (const int4*)(mask + (size_t)q * S_ + jt + sub * KPT);
#pragma unroll
            for (int i = 0; i < 4; ++i) m4[i] = mr[i];
        }
        const int* mb = (const int*)m4;

#pragma unroll
        for (int kk = 0; kk < KPT; ++kk) {
            const int jl = sub * KPT + kk;
            const float4* krow = (const float4*)&Ks[jl][0];
            float s = 0.f;
#pragma unroll
            for (int i = 0; i < 8; ++i) {
                float4 kv = krow[i];
                s += qreg[i].x * kv.x + qreg[i].y * kv.y + qreg[i].z * kv.z + qreg[i].w * kv.w;
            }
            const float p = mb[kk] ? __expf(s * scale) : 0.f;
            lsum0 += p;
            const float4* vrow = (const float4*)&Vs[jl][0];
#pragma unroll
            for (int i = 0; i < 8; ++i) {
                float4 vv = vrow[i];
                o[i * 4 + 0] += p * vv.x;
                o[i * 4 + 1] += p * vv.y;
                o[i * 4 + 2] += p * vv.z;
                o[i * 4 + 3] += p * vv.w;
            }
        }
    }

#pragma unroll
    for (int d = 0; d < D_; ++d) red_o[sub][ql][d] = o[d];
    red_l[sub][ql] = lsum0;
    __syncthreads();

    const int eq = tid & 63;
    const int dg = tid >> 6;
    float acc[8];
#pragma unroll
    for (int i = 0; i < 8; ++i) acc[i] = 0.f;
    float lsum = 0.f;
#pragma unroll
    for (int s2 = 0; s2 < NSUB; ++s2) {
        lsum += red_l[s2][eq];
#pragma unroll
        for (int i = 0; i < 8; ++i) acc[i] += red_o[s2][eq][dg * 8 + i];
    }
    const float inv = 1.0f / lsum;
    float* orow = out + ((size_t)h * S_ + q0 + eq) * D_ + dg * 8;
#pragma unroll
    for (int i = 0; i < 8; ++i) orow[i] = acc[i] * inv;
}

// ---------------- host ----------------

extern "C" void kernel_launch(void* const* d_in, const int* in_sizes, int n_in,
                              void* d_out, int out_size, void* d_ws, size_t ws_size,
                              hipStream_t stream) {
    const float* Q = (const float*)d_in[0];
    const float* K = (const float*)d_in[1];
    const float* V = (const float*)d_in[2];
    const int* mask = (const int*)d_in[3];
    float* out = (float*)d_out;

    const size_t MB = 1024 * 1024;
    if (ws_size < 8 * MB) {
        dim3 grid(S_ / QT, H_);
        sparse_attn_fp32<<<grid, 256, 0, stream>>>(Q, K, V, mask, out);
        return;
    }

    char* ws = (char*)d_ws;
    ushort_t* Qh = (ushort_t*)(ws + 0 * MB);
    ushort_t* Kt = (ushort_t*)(ws + 2 * MB);
    ushort_t* Vt = (ushort_t*)(ws + 4 * MB);
    ushort_t* mlane = (ushort_t*)(ws + 6 * MB);  // 2 MB

    prep_qkv<<<1536, 256, 0, stream>>>(Q, K, V, Qh, Kt, Vt);
    prep_mask<<<1024, 256, 0, stream>>>(mask, mlane);

    dim3 grid(S_ / 64, H_);
    attn_mfma<<<grid, 512, 0, stream>>>(Qh, Kt, Vt, mlane, out);
}